// Round 4
// baseline (1620.317 us; speedup 1.0000x reference)
//
#include <hip/hip_runtime.h>
#include <hip/hip_bf16.h>

#define NN 100000
#define NE 1600000
#define INDIM 128
#define HID 64
#define CHUNK 33334   // nodes per agg2 pass (3 passes)

typedef __hip_bfloat16 bf16;

__device__ __forceinline__ float b2f(bf16 v) { return __bfloat162float(v); }
// flag-aware input load: f32==1 -> fp32 tensor, else bf16 tensor
__device__ __forceinline__ float ldin(const void* p, int i, int f32) {
    return f32 ? ((const float*)p)[i] : b2f(((const bf16*)p)[i]);
}
__device__ __forceinline__ float sigmoidf(float x) { return 1.f / (1.f + __expf(-x)); }
__device__ __forceinline__ float tanh_fast(float x) {
    float e = __expf(2.f * x);
    return 1.f - 2.f / (e + 1.f);
}

// ---------------- dtype sniffer: bf16 view of fp32 data has wild exponents
__global__ void k_sniff(const void* __restrict__ x, int* __restrict__ flag) {
    __shared__ int cnt;
    if (threadIdx.x == 0) cnt = 0;
    __syncthreads();
    const bf16* p = (const bf16*)x;
    int bad = 0;
    for (int i = threadIdx.x; i < 8192; i += 256) {
        float v = b2f(p[i]);
        if (!(fabsf(v) < 1e6f)) bad++;   // catches NaN/inf too
    }
    atomicAdd(&cnt, bad);
    __syncthreads();
    if (threadIdx.x == 0) flag[0] = (cnt > 32) ? 1 : 0;
}

// ---------------- degree (over src, self-loops removed) ----------------
__global__ void k_deg(const int* __restrict__ ei, const void* __restrict__ ew,
                      float* __restrict__ deg, const int* __restrict__ flagp) {
    const int f32 = flagp[0];
    int e = blockIdx.x * 256 + threadIdx.x;   // grid sized exactly NE
    int src = ei[e], dst = ei[NE + e];
    if (src != dst) atomicAdd(deg + src, ldin(ew, e, f32));
}

__global__ void k_dinv(float* __restrict__ buf) {
    int n = blockIdx.x * 256 + threadIdx.x;
    if (n < NN) { float d = buf[n]; buf[n] = d > 0.f ? rsqrtf(d) : 0.f; }
}

// ---------------- SpMM1: all dst, gather h (input dtype), fp32 scatter -
__global__ void k_spmm1(const int* __restrict__ ei, const void* __restrict__ ew,
                        const float* __restrict__ dinv, const void* __restrict__ zin,
                        float* __restrict__ outagg, const int* __restrict__ flagp) {
    const int f32 = flagp[0];
    int gid = blockIdx.x * 256 + threadIdx.x; // grid = NE*64 threads exactly
    int e = gid >> 6, j = gid & 63;
    int src = ei[e], dst = ei[NE + e];
    if (src == dst) return;
    float lw = -dinv[src] * ldin(ew, e, f32) * dinv[dst];
    if (lw == 0.f) return;
    float zv = ldin(zin, src * 64 + j, f32);
    atomicAdd(outagg + dst * 64 + j, lw * zv);
}

// ---------------- SpMM2: dst-chunk-filtered, fp32 gather ---------------
__global__ void k_spmm2(const int* __restrict__ ei, const void* __restrict__ ew,
                        const float* __restrict__ dinv, const float* __restrict__ zin,
                        float* __restrict__ outagg, int lo, int hi,
                        const int* __restrict__ flagp) {
    const int f32 = flagp[0];
    int gid = blockIdx.x * 256 + threadIdx.x;
    int e = gid >> 6, j = gid & 63;
    int src = ei[e], dst = ei[NE + e];
    if (dst < lo || dst >= hi || src == dst) return;
    float lw = -dinv[src] * ldin(ew, e, f32) * dinv[dst];
    if (lw == 0.f) return;
    float zv = zin[src * 64 + j];
    atomicAdd(outagg + (dst - lo) * 64 + j, lw * zv);
}

// ---------------- build concatenated weight [320][256] fp32 ------------
__global__ void k_wcat(const void* __restrict__ Wx, const void* __restrict__ theta,
                       const void* __restrict__ bg, const void* __restrict__ convb,
                       float* __restrict__ Wcat, float* __restrict__ biascat,
                       const int* __restrict__ flagp) {
    const int f32 = flagp[0];
    int gid = blockIdx.x * 256 + threadIdx.x; // 81920 exactly
    int r = gid >> 8, o = gid & 255;
    int g = o >> 6, c = o & 63;
    float v;
    if (r < 128) {
        v = ldin(Wx, (g * 128 + r) * 64 + c, f32);
    } else {
        int k = (r - 128) >> 6, rr = (r - 128) & 63;
        v = ldin(theta, ((g * 3 + k) * 64 + rr) * 64 + c, f32);
    }
    Wcat[r * 256 + o] = v;
    if (gid < 256) biascat[gid] = ldin(bg, gid, f32) + ldin(convb, gid, f32);
}

// ---------------- fused gate GEMM [64 nodes x 256 cols] + LSTM ---------
__global__ __launch_bounds__(256)
void k_gates(const void* __restrict__ x, const void* __restrict__ h,
             const void* __restrict__ cin,
             const float* __restrict__ Tx1, const float* __restrict__ agg2,
             const float* __restrict__ Wcat, const float* __restrict__ biascat,
             float* __restrict__ h0out, float* __restrict__ c0out,
             int lo, int hi, const int* __restrict__ flagp) {
    const int f32 = flagp[0];
    __shared__ float Fs[32 * 68];   // [kk][m], padded stride 68
    __shared__ float Ws[32 * 256];  // [kk][o]
    const int tid = threadIdx.x;
    const int tc = tid & 31, tr = tid >> 5;
    const int base = lo + blockIdx.x * 64;

    float accA[8][4], accB[8][4];
#pragma unroll
    for (int i = 0; i < 4; i++) {
        float bA = biascat[tc * 4 + i];
        float bB = biascat[128 + tc * 4 + i];
#pragma unroll
        for (int q = 0; q < 8; q++) { accA[q][i] = bA; accB[q][i] = bB; }
    }

    for (int ck = 0; ck < 10; ck++) {
        const int K0 = ck * 32;
#pragma unroll
        for (int t = 0; t < 8; t++) {
            int lin4 = tid + 256 * t;
            int kk = lin4 >> 6, o = (lin4 & 63) * 4;
            float4 v = *(const float4*)(Wcat + (K0 + kk) * 256 + o);
            *(float4*)(Ws + kk * 256 + o) = v;
        }
#pragma unroll
        for (int t = 0; t < 8; t++) {
            int lin = tid + 256 * t;
            int m = lin >> 5, kk = lin & 31;
            int node = base + m;
            int r = K0 + kk;
            float v = 0.f;
            if (node < hi) {
                if (r < 128)      v = ldin(x, node * 128 + r, f32);
                else if (r < 192) v = ldin(h, node * 64 + (r - 128), f32);
                else if (r < 256) v = Tx1[node * 64 + (r - 192)];
                else              v = 2.f * agg2[(node - lo) * 64 + (r - 256)]
                                        - ldin(h, node * 64 + (r - 256), f32);
            }
            Fs[kk * 68 + m] = v;
        }
        __syncthreads();
#pragma unroll 4
        for (int kk = 0; kk < 32; kk++) {
            float4 wA = *(const float4*)(Ws + kk * 256 + tc * 4);
            float4 wB = *(const float4*)(Ws + kk * 256 + 128 + tc * 4);
            float4 f0 = *(const float4*)(Fs + kk * 68 + tr * 8);
            float4 f1 = *(const float4*)(Fs + kk * 68 + tr * 8 + 4);
            float fv[8] = {f0.x, f0.y, f0.z, f0.w, f1.x, f1.y, f1.z, f1.w};
            float wa[4] = {wA.x, wA.y, wA.z, wA.w};
            float wb[4] = {wB.x, wB.y, wB.z, wB.w};
#pragma unroll
            for (int q = 0; q < 8; q++)
#pragma unroll
                for (int i = 0; i < 4; i++) {
                    accA[q][i] = fmaf(fv[q], wa[i], accA[q][i]);
                    accB[q][i] = fmaf(fv[q], wb[i], accB[q][i]);
                }
        }
        __syncthreads();
    }

    // LSTM epilogue. gates: 0=i, 1=f, 2=t(candidate), 3=o
    float* itS = Ws; // reuse LDS ([c][m] = 64x64)
    if (tc < 16) {
#pragma unroll
        for (int q = 0; q < 8; q++) {
            int m = tr * 8 + q;
#pragma unroll
            for (int i = 0; i < 4; i++) {
                int c = tc * 4 + i;
                float iv = sigmoidf(accA[q][i]);
                float tv = tanh_fast(accB[q][i]);
                itS[c * 64 + m] = iv * tv;
            }
        }
    }
    __syncthreads();
    if (tc >= 16) {
        int cb = (tc - 16) * 4;
#pragma unroll
        for (int q = 0; q < 8; q++) {
            int m = tr * 8 + q;
            int node = base + m;
            if (node < hi) {
                float4 hv, cv;
                float hs[4], cs[4];
#pragma unroll
                for (int i = 0; i < 4; i++) {
                    int c = cb + i;
                    float fv_ = sigmoidf(accA[q][i]);
                    float ov  = sigmoidf(accB[q][i]);
                    float c0 = fv_ * ldin(cin, node * 64 + c, f32) + itS[c * 64 + m];
                    float h0 = ov * tanh_fast(c0);
                    hs[i] = h0; cs[i] = c0;
                }
                hv.x = hs[0]; hv.y = hs[1]; hv.z = hs[2]; hv.w = hs[3];
                cv.x = cs[0]; cv.y = cs[1]; cv.z = cs[2]; cv.w = cs[3];
                *reinterpret_cast<float4*>(h0out + node * 64 + cb) = hv;
                *reinterpret_cast<float4*>(c0out + node * 64 + cb) = cv;
            }
        }
    }
}

// ---------------- out = relu(h0) @ Wl + bl  (Wl column in VGPRs) -------
__global__ __launch_bounds__(256)
void k_out(const float* __restrict__ h0, const void* __restrict__ Wl,
           const void* __restrict__ bl, float* __restrict__ out,
           const int* __restrict__ flagp) {
    const int f32 = flagp[0];
    int lane = threadIdx.x & 63;
    int wave = (blockIdx.x * blockDim.x + threadIdx.x) >> 6;
    int nwaves = (gridDim.x * blockDim.x) >> 6;
    float wcol[64];
#pragma unroll
    for (int k = 0; k < 64; k++) wcol[k] = ldin(Wl, k * 64 + lane, f32);
    float bias = ldin(bl, lane, f32);
    for (int n = wave; n < NN; n += nwaves) {
        float hv = fmaxf(h0[n * 64 + lane], 0.f);
        float acc = bias;
#pragma unroll
        for (int k = 0; k < 64; k++) {
            float hk = __uint_as_float(__builtin_amdgcn_readlane(__float_as_uint(hv), k));
            acc = fmaf(hk, wcol[k], acc);
        }
        out[n * 64 + lane] = acc;
    }
}

extern "C" void kernel_launch(void* const* d_in, const int* in_sizes, int n_in,
                              void* d_out, int out_size, void* d_ws, size_t ws_size,
                              hipStream_t stream) {
    const void* x     = d_in[0];
    const int*  ei    = (const int*)d_in[1];
    const void* ew    = d_in[2];
    const void* h     = d_in[3];
    const void* c     = d_in[4];
    const void* Wx    = d_in[5];
    const void* bg    = d_in[6];
    const void* theta = d_in[7];
    const void* convb = d_in[8];
    const void* Wl    = d_in[9];
    const void* bl    = d_in[10];
    (void)in_sizes; (void)n_in; (void)out_size; (void)ws_size;

    // ws layout (floats) — total 2,315,616 floats = 9.26 MB (< 12.9 MB proven safe)
    float* ws    = (float*)d_ws;
    int*   flag  = (int*)ws;                 // [0,64)
    float* deg   = ws + 64;                  // 100,000
    float* Wcat  = ws + 100064;              // 81,920
    float* biasc = ws + 181984;              // 256
    float* agg2c = ws + 182240;              // CHUNK*64 = 2,133,376

    // d_out is FP32: out [0,6.4M) | h0 [6.4M,12.8M) | c0 [12.8M,19.2M) floats
    float* outF = (float*)d_out;
    float* h0o  = outF + (size_t)NN * 64;
    float* c0o  = outF + (size_t)2 * NN * 64;
    float* Tx1f = outF;   // alias: Tx1 lives in the `out` region until k_out

    k_sniff<<<1, 256, 0, stream>>>(x, flag);
    hipMemsetAsync(deg, 0, (size_t)100000 * 4, stream);
    hipMemsetAsync(Tx1f, 0, (size_t)6400000 * 4, stream);

    k_deg<<<NE / 256, 256, 0, stream>>>(ei, ew, deg, flag);
    k_dinv<<<(NN + 255) / 256, 256, 0, stream>>>(deg);
    k_spmm1<<<NE / 4, 256, 0, stream>>>(ei, ew, deg, h, Tx1f, flag);
    k_wcat<<<320, 256, 0, stream>>>(Wx, theta, bg, convb, Wcat, biasc, flag);

    for (int chunk = 0; chunk < 3; chunk++) {
        int lo = chunk * CHUNK;
        int hi = (lo + CHUNK < NN) ? lo + CHUNK : NN;
        hipMemsetAsync(agg2c, 0, (size_t)CHUNK * 64 * 4, stream);
        k_spmm2<<<NE / 4, 256, 0, stream>>>(ei, ew, deg, Tx1f, agg2c, lo, hi, flag);
        k_gates<<<(hi - lo + 63) / 64, 256, 0, stream>>>(x, h, c, Tx1f, agg2c,
                                                         Wcat, biasc, h0o, c0o,
                                                         lo, hi, flag);
    }
    k_out<<<512, 256, 0, stream>>>(h0o, Wl, bl, outF, flag);
}

// Round 5
// 1128.127 us; speedup vs baseline: 1.4363x; 1.4363x over previous
//
#include <hip/hip_runtime.h>
#include <hip/hip_bf16.h>

#define NN 100000
#define NE 1600000
#define INDIM 128
#define HID 64

typedef __hip_bfloat16 bf16;

__device__ __forceinline__ float b2f(bf16 v) { return __bfloat162float(v); }
// flag-aware input load: f32==1 -> fp32 tensor, else bf16 tensor
__device__ __forceinline__ float ldin(const void* p, int i, int f32) {
    return f32 ? ((const float*)p)[i] : b2f(((const bf16*)p)[i]);
}
__device__ __forceinline__ float sigmoidf(float x) { return 1.f / (1.f + __expf(-x)); }
__device__ __forceinline__ float tanh_fast(float x) {
    float e = __expf(2.f * x);
    return 1.f - 2.f / (e + 1.f);
}

// ---------------- dtype sniffer ----------------------------------------
__global__ void k_sniff(const void* __restrict__ x, int* __restrict__ flag) {
    __shared__ int cnt;
    if (threadIdx.x == 0) cnt = 0;
    __syncthreads();
    const bf16* p = (const bf16*)x;
    int bad = 0;
    for (int i = threadIdx.x; i < 8192; i += 256) {
        float v = b2f(p[i]);
        if (!(fabsf(v) < 1e6f)) bad++;
    }
    atomicAdd(&cnt, bad);
    __syncthreads();
    if (threadIdx.x == 0) flag[0] = (cnt > 32) ? 1 : 0;
}

// ---------------- degree (over src) + in-degree histogram (over dst) ---
__global__ void k_deghist(const int* __restrict__ ei, const void* __restrict__ ew,
                          float* __restrict__ deg, int* __restrict__ cnt,
                          const int* __restrict__ flagp) {
    const int f32 = flagp[0];
    int e = blockIdx.x * 256 + threadIdx.x;   // grid exactly NE
    int src = ei[e], dst = ei[NE + e];
    if (src != dst) {
        atomicAdd(deg + src, ldin(ew, e, f32));
        atomicAdd(cnt + dst, 1);
    }
}

__global__ void k_dinv(float* __restrict__ buf) {
    int n = blockIdx.x * 256 + threadIdx.x;
    if (n < NN) { float d = buf[n]; buf[n] = d > 0.f ? rsqrtf(d) : 0.f; }
}

// ---------------- single-block prefix scan: cnt -> rowptr, wptr --------
__global__ __launch_bounds__(1024)
void k_scan(const int* __restrict__ cnt, int* __restrict__ rowptr,
            int* __restrict__ wptr) {
    __shared__ int ps[1024];
    const int t = threadIdx.x;
    const int lo = t * 98;
    const int hi = (lo + 98 < NN) ? lo + 98 : NN;
    int s = 0;
    for (int i = lo; i < hi; i++) s += cnt[i];
    int own = s;
    ps[t] = s;
    __syncthreads();
    for (int off = 1; off < 1024; off <<= 1) {
        int v = (t >= off) ? ps[t - off] : 0;
        __syncthreads();
        ps[t] += v;
        __syncthreads();
    }
    int run = ps[t] - own;   // exclusive base for this thread's chunk
    for (int i = lo; i < hi; i++) {
        rowptr[i] = run; wptr[i] = run;
        run += cnt[i];
    }
    if (t == 0) rowptr[NN] = ps[1023];
}

// ---------------- fill CSR: packed (src, lw) per dst slot --------------
__global__ void k_fill(const int* __restrict__ ei, const void* __restrict__ ew,
                       const float* __restrict__ dinv, int* __restrict__ wptr,
                       int2* __restrict__ csr, const int* __restrict__ flagp) {
    const int f32 = flagp[0];
    int e = blockIdx.x * 256 + threadIdx.x;   // grid exactly NE
    int src = ei[e], dst = ei[NE + e];
    if (src == dst) return;
    float lw = -dinv[src] * ldin(ew, e, f32) * dinv[dst];
    int pos = atomicAdd(wptr + dst, 1);
    int2 p; p.x = src; p.y = __float_as_int(lw);
    csr[pos] = p;
}

// ---------------- gather SpMM: one wave per dst, register accumulate ---
template<bool BF16IN>
__global__ __launch_bounds__(256)
void k_gath(const int* __restrict__ rowptr, const int2* __restrict__ csr,
            const void* __restrict__ zin, float* __restrict__ outv,
            const int* __restrict__ flagp) {
    const int f32 = flagp[0];
    int w = (blockIdx.x * 256 + threadIdx.x) >> 6;   // dst node
    int lane = threadIdx.x & 63;
    if (w >= NN) return;
    int b = rowptr[w], e = rowptr[w + 1];
    float acc = 0.f;
    int i = b;
    for (; i + 1 < e; i += 2) {
        int2 p0 = csr[i], p1 = csr[i + 1];
        float z0 = BF16IN ? ldin(zin, p0.x * 64 + lane, f32)
                          : ((const float*)zin)[p0.x * 64 + lane];
        float z1 = BF16IN ? ldin(zin, p1.x * 64 + lane, f32)
                          : ((const float*)zin)[p1.x * 64 + lane];
        acc = fmaf(__int_as_float(p0.y), z0, acc);
        acc = fmaf(__int_as_float(p1.y), z1, acc);
    }
    if (i < e) {
        int2 p0 = csr[i];
        float z0 = BF16IN ? ldin(zin, p0.x * 64 + lane, f32)
                          : ((const float*)zin)[p0.x * 64 + lane];
        acc = fmaf(__int_as_float(p0.y), z0, acc);
    }
    outv[w * 64 + lane] = acc;
}

// ---------------- build concatenated weight [320][256] fp32 ------------
__global__ void k_wcat(const void* __restrict__ Wx, const void* __restrict__ theta,
                       const void* __restrict__ bg, const void* __restrict__ convb,
                       float* __restrict__ Wcat, float* __restrict__ biascat,
                       const int* __restrict__ flagp) {
    const int f32 = flagp[0];
    int gid = blockIdx.x * 256 + threadIdx.x; // 81920 exactly
    int r = gid >> 8, o = gid & 255;
    int g = o >> 6, c = o & 63;
    float v;
    if (r < 128) {
        v = ldin(Wx, (g * 128 + r) * 64 + c, f32);
    } else {
        int k = (r - 128) >> 6, rr = (r - 128) & 63;
        v = ldin(theta, ((g * 3 + k) * 64 + rr) * 64 + c, f32);
    }
    Wcat[r * 256 + o] = v;
    if (gid < 256) biascat[gid] = ldin(bg, gid, f32) + ldin(convb, gid, f32);
}

// ---------------- fused gate GEMM [64 nodes x 256 cols] + LSTM ---------
// NOTE: agg2 aliases c0out (same node rows). All agg2 reads happen in the
// K-loop staging (before the final __syncthreads); c0out writes happen in
// the epilogue after it; blocks own disjoint node slabs -> safe.
__global__ __launch_bounds__(256)
void k_gates(const void* __restrict__ x, const void* __restrict__ h,
             const void* __restrict__ cin,
             const float* __restrict__ Tx1, const float* __restrict__ agg2,
             const float* __restrict__ Wcat, const float* __restrict__ biascat,
             float* __restrict__ h0out, float* __restrict__ c0out,
             const int* __restrict__ flagp) {
    const int f32 = flagp[0];
    __shared__ float Fs[32 * 68];   // [kk][m], padded stride 68
    __shared__ float Ws[32 * 256];  // [kk][o]
    const int tid = threadIdx.x;
    const int tc = tid & 31, tr = tid >> 5;
    const int base = blockIdx.x * 64;

    float accA[8][4], accB[8][4];
#pragma unroll
    for (int i = 0; i < 4; i++) {
        float bA = biascat[tc * 4 + i];
        float bB = biascat[128 + tc * 4 + i];
#pragma unroll
        for (int q = 0; q < 8; q++) { accA[q][i] = bA; accB[q][i] = bB; }
    }

    for (int ck = 0; ck < 10; ck++) {
        const int K0 = ck * 32;
#pragma unroll
        for (int t = 0; t < 8; t++) {
            int lin4 = tid + 256 * t;
            int kk = lin4 >> 6, o = (lin4 & 63) * 4;
            float4 v = *(const float4*)(Wcat + (K0 + kk) * 256 + o);
            *(float4*)(Ws + kk * 256 + o) = v;
        }
#pragma unroll
        for (int t = 0; t < 8; t++) {
            int lin = tid + 256 * t;
            int m = lin >> 5, kk = lin & 31;
            int node = base + m;
            int r = K0 + kk;
            float v = 0.f;
            if (node < NN) {
                if (r < 128)      v = ldin(x, node * 128 + r, f32);
                else if (r < 192) v = ldin(h, node * 64 + (r - 128), f32);
                else if (r < 256) v = Tx1[node * 64 + (r - 192)];
                else              v = 2.f * agg2[node * 64 + (r - 256)]
                                        - ldin(h, node * 64 + (r - 256), f32);
            }
            Fs[kk * 68 + m] = v;
        }
        __syncthreads();
#pragma unroll 4
        for (int kk = 0; kk < 32; kk++) {
            float4 wA = *(const float4*)(Ws + kk * 256 + tc * 4);
            float4 wB = *(const float4*)(Ws + kk * 256 + 128 + tc * 4);
            float4 f0 = *(const float4*)(Fs + kk * 68 + tr * 8);
            float4 f1 = *(const float4*)(Fs + kk * 68 + tr * 8 + 4);
            float fv[8] = {f0.x, f0.y, f0.z, f0.w, f1.x, f1.y, f1.z, f1.w};
            float wa[4] = {wA.x, wA.y, wA.z, wA.w};
            float wb[4] = {wB.x, wB.y, wB.z, wB.w};
#pragma unroll
            for (int q = 0; q < 8; q++)
#pragma unroll
                for (int i = 0; i < 4; i++) {
                    accA[q][i] = fmaf(fv[q], wa[i], accA[q][i]);
                    accB[q][i] = fmaf(fv[q], wb[i], accB[q][i]);
                }
        }
        __syncthreads();
    }

    // LSTM epilogue. gates: 0=i, 1=f, 2=t(candidate), 3=o
    float* itS = Ws; // reuse LDS ([c][m] = 64x64)
    if (tc < 16) {
#pragma unroll
        for (int q = 0; q < 8; q++) {
            int m = tr * 8 + q;
#pragma unroll
            for (int i = 0; i < 4; i++) {
                int c = tc * 4 + i;
                float iv = sigmoidf(accA[q][i]);
                float tv = tanh_fast(accB[q][i]);
                itS[c * 64 + m] = iv * tv;
            }
        }
    }
    __syncthreads();
    if (tc >= 16) {
        int cb = (tc - 16) * 4;
#pragma unroll
        for (int q = 0; q < 8; q++) {
            int m = tr * 8 + q;
            int node = base + m;
            if (node < NN) {
                float hs[4], cs[4];
#pragma unroll
                for (int i = 0; i < 4; i++) {
                    int c = cb + i;
                    float fv_ = sigmoidf(accA[q][i]);
                    float ov  = sigmoidf(accB[q][i]);
                    float c0 = fv_ * ldin(cin, node * 64 + c, f32) + itS[c * 64 + m];
                    float h0 = ov * tanh_fast(c0);
                    hs[i] = h0; cs[i] = c0;
                }
                float4 hv = {hs[0], hs[1], hs[2], hs[3]};
                float4 cv = {cs[0], cs[1], cs[2], cs[3]};
                *reinterpret_cast<float4*>(h0out + node * 64 + cb) = hv;
                *reinterpret_cast<float4*>(c0out + node * 64 + cb) = cv;
            }
        }
    }
}

// ---------------- out = relu(h0) @ Wl + bl  (Wl column in VGPRs) -------
__global__ __launch_bounds__(256)
void k_out(const float* __restrict__ h0, const void* __restrict__ Wl,
           const void* __restrict__ bl, float* __restrict__ out,
           const int* __restrict__ flagp) {
    const int f32 = flagp[0];
    int lane = threadIdx.x & 63;
    int wave = (blockIdx.x * blockDim.x + threadIdx.x) >> 6;
    int nwaves = (gridDim.x * blockDim.x) >> 6;
    float wcol[64];
#pragma unroll
    for (int k = 0; k < 64; k++) wcol[k] = ldin(Wl, k * 64 + lane, f32);
    float bias = ldin(bl, lane, f32);
    for (int n = wave; n < NN; n += nwaves) {
        float hv = fmaxf(h0[n * 64 + lane], 0.f);
        float acc = bias;
#pragma unroll
        for (int k = 0; k < 64; k++) {
            float hk = __uint_as_float(__builtin_amdgcn_readlane(__float_as_uint(hv), k));
            acc = fmaf(hk, wcol[k], acc);
        }
        out[n * 64 + lane] = acc;
    }
}

extern "C" void kernel_launch(void* const* d_in, const int* in_sizes, int n_in,
                              void* d_out, int out_size, void* d_ws, size_t ws_size,
                              hipStream_t stream) {
    const void* x     = d_in[0];
    const int*  ei    = (const int*)d_in[1];
    const void* ew    = d_in[2];
    const void* h     = d_in[3];
    const void* c     = d_in[4];
    const void* Wx    = d_in[5];
    const void* bg    = d_in[6];
    const void* theta = d_in[7];
    const void* convb = d_in[8];
    const void* Wl    = d_in[9];
    const void* bl    = d_in[10];
    (void)in_sizes; (void)n_in; (void)out_size; (void)ws_size;

    // ws layout (4B words) — total ~1.93 MB (well under proven-safe 12.9 MB)
    float* ws     = (float*)d_ws;
    int*   flag   = (int*)ws;                 // 64
    float* deg    = ws + 64;                  // 100000 (-> dinv in place)
    int*   cnt    = (int*)(ws + 100064);      // 100000
    int*   rowptr = (int*)(ws + 200064);      // 100001 (padded to 100064)
    int*   wptr   = (int*)(ws + 300128);      // 100000
    float* Wcat   = ws + 400128;              // 81920
    float* biasc  = ws + 482048;              // 256

    // d_out is FP32: out [0,6.4M) | h0 [6.4M,12.8M) | c0 [12.8M,19.2M) floats
    float* outF = (float*)d_out;
    float* h0o  = outF + (size_t)NN * 64;
    float* c0o  = outF + (size_t)2 * NN * 64;
    // scratch aliases inside d_out (dead ranges at time of use):
    float* Tx1f = outF;                       // Tx1 in `out` region until k_out
    int2*  csr  = (int2*)h0o;                 // 1.6M int2 = 12.8MB in h0 region
    float* agg2 = c0o;                        // full agg2 in c0 region

    k_sniff<<<1, 256, 0, stream>>>(x, flag);
    hipMemsetAsync(deg, 0, (size_t)200000 * 4, stream);  // deg + cnt contiguous

    k_deghist<<<NE / 256, 256, 0, stream>>>(ei, ew, deg, cnt, flag);
    k_dinv<<<(NN + 255) / 256, 256, 0, stream>>>(deg);
    k_scan<<<1, 1024, 0, stream>>>(cnt, rowptr, wptr);
    k_fill<<<NE / 256, 256, 0, stream>>>(ei, ew, deg, wptr, csr, flag);
    k_wcat<<<320, 256, 0, stream>>>(Wx, theta, bg, convb, Wcat, biasc, flag);

    k_gath<true ><<<25000, 256, 0, stream>>>(rowptr, csr, h,    Tx1f, flag);
    k_gath<false><<<25000, 256, 0, stream>>>(rowptr, csr, Tx1f, agg2, flag);

    k_gates<<<(NN + 63) / 64, 256, 0, stream>>>(x, h, c, Tx1f, agg2,
                                                Wcat, biasc, h0o, c0o, flag);
    k_out<<<512, 256, 0, stream>>>(h0o, Wl, bl, outF, flag);
}

// Round 6
// 914.125 us; speedup vs baseline: 1.7725x; 1.2341x over previous
//
#include <hip/hip_runtime.h>
#include <hip/hip_bf16.h>

#define NN 100000
#define NE 1600000
#define INDIM 128
#define HID 64

typedef __hip_bfloat16 bf16;
typedef unsigned short ushort;
typedef unsigned int uint;
typedef __attribute__((ext_vector_type(8))) short short8;
typedef __attribute__((ext_vector_type(4))) float floatx4;

__device__ __forceinline__ float b2f(bf16 v) { return __bfloat162float(v); }
__device__ __forceinline__ float b2f_raw(ushort u) { return __uint_as_float(((uint)u) << 16); }
__device__ __forceinline__ ushort f2bu(float v) {
    bf16 t = __float2bfloat16(v);
    return *reinterpret_cast<ushort*>(&t);
}
// flag-aware input load: f32==1 -> fp32 tensor, else bf16 tensor
__device__ __forceinline__ float ldin(const void* p, int i, int f32) {
    return f32 ? ((const float*)p)[i] : b2f(((const bf16*)p)[i]);
}
__device__ __forceinline__ float sigmoidf(float x) { return 1.f / (1.f + __expf(-x)); }
__device__ __forceinline__ float tanh_fast(float x) {
    float e = __expf(2.f * x);
    return 1.f - 2.f / (e + 1.f);
}
__device__ __forceinline__ uint4 packf8(const float* f) {
    uint4 u;
    u.x = f2bu(f[0]) | ((uint)f2bu(f[1]) << 16);
    u.y = f2bu(f[2]) | ((uint)f2bu(f[3]) << 16);
    u.z = f2bu(f[4]) | ((uint)f2bu(f[5]) << 16);
    u.w = f2bu(f[6]) | ((uint)f2bu(f[7]) << 16);
    return u;
}
// 8 consecutive elements of a (bf16|fp32) tensor as packed bf16
__device__ __forceinline__ uint4 ld8_bf16(const void* p, int off, int f32) {
    if (!f32) return *(const uint4*)((const ushort*)p + off);
    const float* q = (const float*)p + off;
    float4 a = *(const float4*)q, b = *(const float4*)(q + 4);
    float f[8] = {a.x, a.y, a.z, a.w, b.x, b.y, b.z, b.w};
    return packf8(f);
}

// ---------------- dtype sniffer ----------------------------------------
__global__ void k_sniff(const void* __restrict__ x, int* __restrict__ flag) {
    __shared__ int cnt;
    if (threadIdx.x == 0) cnt = 0;
    __syncthreads();
    const bf16* p = (const bf16*)x;
    int bad = 0;
    for (int i = threadIdx.x; i < 8192; i += 256) {
        float v = b2f(p[i]);
        if (!(fabsf(v) < 1e6f)) bad++;
    }
    atomicAdd(&cnt, bad);
    __syncthreads();
    if (threadIdx.x == 0) flag[0] = (cnt > 32) ? 1 : 0;
}

// ---------------- degree (over src) + in-degree histogram (over dst) ---
__global__ void k_deghist(const int* __restrict__ ei, const void* __restrict__ ew,
                          float* __restrict__ deg, int* __restrict__ cnt,
                          const int* __restrict__ flagp) {
    const int f32 = flagp[0];
    int e = blockIdx.x * 256 + threadIdx.x;   // grid exactly NE
    int src = ei[e], dst = ei[NE + e];
    if (src != dst) {
        atomicAdd(deg + src, ldin(ew, e, f32));
        atomicAdd(cnt + dst, 1);
    }
}

__global__ void k_dinv(float* __restrict__ buf) {
    int n = blockIdx.x * 256 + threadIdx.x;
    if (n < NN) { float d = buf[n]; buf[n] = d > 0.f ? rsqrtf(d) : 0.f; }
}

// ---------------- single-block prefix scan: cnt -> rowptr, wptr --------
__global__ __launch_bounds__(1024)
void k_scan(const int* __restrict__ cnt, int* __restrict__ rowptr,
            int* __restrict__ wptr) {
    __shared__ int ps[1024];
    const int t = threadIdx.x;
    const int lo = t * 98;
    const int hi = (lo + 98 < NN) ? lo + 98 : NN;
    int s = 0;
    for (int i = lo; i < hi; i++) s += cnt[i];
    int own = s;
    ps[t] = s;
    __syncthreads();
    for (int off = 1; off < 1024; off <<= 1) {
        int v = (t >= off) ? ps[t - off] : 0;
        __syncthreads();
        ps[t] += v;
        __syncthreads();
    }
    int run = ps[t] - own;
    for (int i = lo; i < hi; i++) {
        rowptr[i] = run; wptr[i] = run;
        run += cnt[i];
    }
    if (t == 0) rowptr[NN] = ps[1023];
}

// ---------------- fill CSR: packed (src, lw) per dst slot --------------
__global__ void k_fill(const int* __restrict__ ei, const void* __restrict__ ew,
                       const float* __restrict__ dinv, int* __restrict__ wptr,
                       int2* __restrict__ csr, const int* __restrict__ flagp) {
    const int f32 = flagp[0];
    int e = blockIdx.x * 256 + threadIdx.x;   // grid exactly NE
    int src = ei[e], dst = ei[NE + e];
    if (src == dst) return;
    float lw = -dinv[src] * ldin(ew, e, f32) * dinv[dst];
    int pos = atomicAdd(wptr + dst, 1);
    int2 p; p.x = src; p.y = __float_as_int(lw);
    csr[pos] = p;
}

// ---------------- gather SpMM: one wave per dst, register accumulate ---
template<bool BF16IN>
__global__ __launch_bounds__(256)
void k_gath(const int* __restrict__ rowptr, const int2* __restrict__ csr,
            const void* __restrict__ zin, float* __restrict__ outv,
            const int* __restrict__ flagp) {
    const int f32 = flagp[0];
    int w = (blockIdx.x * 256 + threadIdx.x) >> 6;   // dst node
    int lane = threadIdx.x & 63;
    if (w >= NN) return;
    int b = rowptr[w], e = rowptr[w + 1];
    float acc = 0.f;
    int i = b;
    for (; i + 1 < e; i += 2) {
        int2 p0 = csr[i], p1 = csr[i + 1];
        float z0 = BF16IN ? ldin(zin, p0.x * 64 + lane, f32)
                          : ((const float*)zin)[p0.x * 64 + lane];
        float z1 = BF16IN ? ldin(zin, p1.x * 64 + lane, f32)
                          : ((const float*)zin)[p1.x * 64 + lane];
        acc = fmaf(__int_as_float(p0.y), z0, acc);
        acc = fmaf(__int_as_float(p1.y), z1, acc);
    }
    if (i < e) {
        int2 p0 = csr[i];
        float z0 = BF16IN ? ldin(zin, p0.x * 64 + lane, f32)
                          : ((const float*)zin)[p0.x * 64 + lane];
        acc = fmaf(__int_as_float(p0.y), z0, acc);
    }
    outv[w * 64 + lane] = acc;
}

// ---------------- pre-swizzle weights into MFMA fragment order ---------
// Wf: [kc 0..9][t 0..15][lane 0..63][j 0..7] bf16, element =
//     W[r = kc*32 + (lane>>4)*8 + j][o = 16t + (lane&15)] with column perm
//     o = 16t+(l&15): gate g = t&3, cc = (t>>2)*16 + (lane&15)
// WlF: [kc2 0..1][t 0..3][lane][j], Wl[k = kc2*32+(l>>4)*8+j][n = 16t+(l&15)]
// biasP[o]: permuted bias
__global__ void k_wcat(const void* __restrict__ Wx, const void* __restrict__ theta,
                       const void* __restrict__ bg, const void* __restrict__ convb,
                       const void* __restrict__ Wl,
                       ushort* __restrict__ Wf, float* __restrict__ biasP,
                       ushort* __restrict__ WlF, const int* __restrict__ flagp) {
    const int f32 = flagp[0];
    int gid = blockIdx.x * 256 + threadIdx.x;   // 336 blocks * 256 = 86016
    if (gid < 81920) {
        int j = gid & 7, l = (gid >> 3) & 63, tile = gid >> 9;
        int kc = tile >> 4, t = tile & 15;
        int r = kc * 32 + ((l >> 4) * 8) + j;
        int g = t & 3;
        int cc = (t >> 2) * 16 + (l & 15);
        float v;
        if (r < 128) {
            v = ldin(Wx, (g * 128 + r) * 64 + cc, f32);
        } else {
            int k3 = (r - 128) >> 6, rr = (r - 128) & 63;
            v = ldin(theta, ((g * 3 + k3) * 64 + rr) * 64 + cc, f32);
        }
        Wf[gid] = f2bu(v);
        if (gid < 256) {
            int o = gid;
            int gg = (o >> 4) & 3;
            int cc2 = (o >> 6) * 16 + (o & 15);
            biasP[o] = ldin(bg, gg * 64 + cc2, f32) + ldin(convb, gg * 64 + cc2, f32);
        }
    } else {
        int gid2 = gid - 81920;                  // [0, 4096)
        int j = gid2 & 7, l = (gid2 >> 3) & 63, tile2 = gid2 >> 9;
        int kc2 = tile2 >> 2, t = tile2 & 3;
        int k = kc2 * 32 + ((l >> 4) * 8) + j;
        int n = t * 16 + (l & 15);
        WlF[gid2] = f2bu(ldin(Wl, k * 64 + n, f32));
    }
}

// ---------------- MFMA gate GEMM [64 nodes x 256 cols] + LSTM + out ----
// F rows: 0-127 x | 128-191 h | 192-255 Tx1 | 256-319 (2*agg2 - h)
// Aliasing: Tx1 lives in `out` fp32 region, agg2 in `c0` fp32 region —
// same-dtype same-row mapping, blocks only touch their own 64-node slab,
// all reads precede all writes within the block. Safe.
__global__ __launch_bounds__(256)
void k_gates(const void* __restrict__ x, const void* __restrict__ h,
             const void* __restrict__ cin,
             const float* __restrict__ Tx1, const float* __restrict__ agg2,
             const ushort* __restrict__ Wf, const float* __restrict__ biasP,
             const ushort* __restrict__ WlF, const void* __restrict__ bl,
             float* __restrict__ outF, float* __restrict__ h0o,
             float* __restrict__ c0o, const int* __restrict__ flagp) {
    const int f32 = flagp[0];
    __shared__ ushort As[4 * 64 * 8];    // 4 KB, A fragments for one 64x32 chunk
    __shared__ ushort Hs[64 * 72];       // 9.2 KB, relu(h0) bf16, padded stride 72
    const int tid = threadIdx.x;
    const int lane = tid & 63;
    const int w = tid >> 6;              // wave 0..3
    const int base = blockIdx.x * 64;
    // staging role: thread -> (node sm, k-quad skq)
    const int sm = tid & 63;
    const int skq = tid >> 6;
    const int snode = base + sm;
    const bool svalid = snode < NN;
    uint4* sdst = (uint4*)&As[(((sm >> 4) * 64) + ((sm & 15) + 16 * skq)) * 8];

    floatx4 acc[4][4];                   // [m-tile][gate]
    {
        float bv0 = biasP[w * 64 + 0 * 16 + (lane & 15)];
        float bv1 = biasP[w * 64 + 1 * 16 + (lane & 15)];
        float bv2 = biasP[w * 64 + 2 * 16 + (lane & 15)];
        float bv3 = biasP[w * 64 + 3 * 16 + (lane & 15)];
#pragma unroll
        for (int mt = 0; mt < 4; mt++) {
            acc[mt][0] = (floatx4){bv0, bv0, bv0, bv0};
            acc[mt][1] = (floatx4){bv1, bv1, bv1, bv1};
            acc[mt][2] = (floatx4){bv2, bv2, bv2, bv2};
            acc[mt][3] = (floatx4){bv3, bv3, bv3, bv3};
        }
    }

    for (int kc = 0; kc < 10; kc++) {
        // ---- produce this thread's 8 bf16 F-values (global loads) ----
        uint4 raw = {0, 0, 0, 0};
        if (svalid) {
            if (kc < 4) {
                raw = ld8_bf16(x, snode * 128 + kc * 32 + skq * 8, f32);
            } else if (kc < 6) {
                raw = ld8_bf16(h, snode * 64 + (kc - 4) * 32 + skq * 8, f32);
            } else if (kc < 8) {
                const float* p = Tx1 + snode * 64 + (kc - 6) * 32 + skq * 8;
                float4 a = *(const float4*)p, b = *(const float4*)(p + 4);
                float f[8] = {a.x, a.y, a.z, a.w, b.x, b.y, b.z, b.w};
                raw = packf8(f);
            } else {
                int off = snode * 64 + (kc - 8) * 32 + skq * 8;
                const float* pa = agg2 + off;
                float4 a = *(const float4*)pa, b = *(const float4*)(pa + 4);
                float av[8] = {a.x, a.y, a.z, a.w, b.x, b.y, b.z, b.w};
                float hv[8];
                if (f32) {
                    const float* ph = (const float*)h + off;
                    float4 h0_ = *(const float4*)ph, h1_ = *(const float4*)(ph + 4);
                    hv[0]=h0_.x; hv[1]=h0_.y; hv[2]=h0_.z; hv[3]=h0_.w;
                    hv[4]=h1_.x; hv[5]=h1_.y; hv[6]=h1_.z; hv[7]=h1_.w;
                } else {
                    uint4 hr = *(const uint4*)((const ushort*)h + off);
                    uint u[4] = {hr.x, hr.y, hr.z, hr.w};
#pragma unroll
                    for (int q = 0; q < 4; q++) {
                        hv[2*q]   = b2f_raw((ushort)(u[q] & 0xffff));
                        hv[2*q+1] = b2f_raw((ushort)(u[q] >> 16));
                    }
                }
                float f[8];
#pragma unroll
                for (int j = 0; j < 8; j++) f[j] = 2.f * av[j] - hv[j];
                raw = packf8(f);
            }
        }
        // ---- B fragments for this chunk (global, L2-resident) ----
        short8 bF[4];
#pragma unroll
        for (int g = 0; g < 4; g++)
            bF[g] = *(const short8*)&Wf[((kc * 16 + w * 4 + g) * 64 + lane) * 8];

        __syncthreads();                 // prior chunk's reads complete
        *sdst = raw;
        __syncthreads();                 // staging visible

        short8 aF[4];
#pragma unroll
        for (int mt = 0; mt < 4; mt++)
            aF[mt] = *(const short8*)&As[(mt * 64 + lane) * 8];
#pragma unroll
        for (int mt = 0; mt < 4; mt++)
#pragma unroll
            for (int g = 0; g < 4; g++)
                acc[mt][g] = __builtin_amdgcn_mfma_f32_16x16x32_bf16(
                    aF[mt], bF[g], acc[mt][g], 0, 0, 0);
    }

    // ---- LSTM epilogue, fully in-register (perm put all 4 gates here) ----
    const int cc = w * 16 + (lane & 15);
#pragma unroll
    for (int mt = 0; mt < 4; mt++) {
        const int m0 = mt * 16 + ((lane >> 4) * 4);
#pragma unroll
        for (int r = 0; r < 4; r++) {
            int ml = m0 + r;
            int node = base + ml;
            float gi = sigmoidf(acc[mt][0][r]);
            float gf = sigmoidf(acc[mt][1][r]);
            float gt = tanh_fast(acc[mt][2][r]);
            float go = sigmoidf(acc[mt][3][r]);
            float cv = (node < NN) ? ldin(cin, node * 64 + cc, f32) : 0.f;
            float c0 = gf * cv + gi * gt;
            float h0v = go * tanh_fast(c0);
            if (node < NN) {
                c0o[node * 64 + cc] = c0;
                h0o[node * 64 + cc] = h0v;
            }
            Hs[ml * 72 + cc] = f2bu(fmaxf(h0v, 0.f));
        }
    }
    __syncthreads();

    // ---- fused out = relu(h0) @ Wl + bl (8 MFMA per wave) ----
    float blv = ldin(bl, w * 16 + (lane & 15), f32);
    floatx4 oacc[4];
#pragma unroll
    for (int mt = 0; mt < 4; mt++) oacc[mt] = (floatx4){blv, blv, blv, blv};
#pragma unroll
    for (int kc2 = 0; kc2 < 2; kc2++) {
        short8 bW = *(const short8*)&WlF[((kc2 * 4 + w) * 64 + lane) * 8];
#pragma unroll
        for (int mt = 0; mt < 4; mt++) {
            short8 aH = *(const short8*)&Hs[(mt * 16 + (lane & 15)) * 72
                                            + kc2 * 32 + (lane >> 4) * 8];
            oacc[mt] = __builtin_amdgcn_mfma_f32_16x16x32_bf16(
                aH, bW, oacc[mt], 0, 0, 0);
        }
    }
#pragma unroll
    for (int mt = 0; mt < 4; mt++) {
        const int m0 = mt * 16 + ((lane >> 4) * 4);
#pragma unroll
        for (int r = 0; r < 4; r++) {
            int node = base + m0 + r;
            if (node < NN)
                outF[node * 64 + w * 16 + (lane & 15)] = oacc[mt][r];
        }
    }
}

extern "C" void kernel_launch(void* const* d_in, const int* in_sizes, int n_in,
                              void* d_out, int out_size, void* d_ws, size_t ws_size,
                              hipStream_t stream) {
    const void* x     = d_in[0];
    const int*  ei    = (const int*)d_in[1];
    const void* ew    = d_in[2];
    const void* h     = d_in[3];
    const void* c     = d_in[4];
    const void* Wx    = d_in[5];
    const void* bg    = d_in[6];
    const void* theta = d_in[7];
    const void* convb = d_in[8];
    const void* Wl    = d_in[9];
    const void* bl    = d_in[10];
    (void)in_sizes; (void)n_in; (void)out_size; (void)ws_size;

    // ws layout (4B words) — ~1.78 MB total
    float*  ws     = (float*)d_ws;
    int*    flag   = (int*)ws;                 // 64
    float*  deg    = ws + 64;                  // 100000 (-> dinv in place)
    int*    cnt    = (int*)(ws + 100064);      // 100000
    int*    rowptr = (int*)(ws + 200064);      // 100001 (pad to 100064)
    int*    wptr   = (int*)(ws + 300128);      // 100000
    float*  biasP  = ws + 400128;              // 256
    ushort* Wf     = (ushort*)(ws + 400384);   // 81920 ushort = 40960 words
    ushort* WlF    = (ushort*)(ws + 441344);   // 4096 ushort = 2048 words

    // d_out FP32: out [0,6.4M) | h0 [6.4M,12.8M) | c0 [12.8M,19.2M)
    float* outF = (float*)d_out;
    float* h0o  = outF + (size_t)NN * 64;
    float* c0o  = outF + (size_t)2 * NN * 64;
    float* Tx1f = outF;          // alias (same-row fp32 mapping)
    int2*  csr  = (int2*)h0o;    // read-complete before k_gates
    float* agg2 = c0o;           // alias (same-row fp32 mapping)

    k_sniff<<<1, 256, 0, stream>>>(x, flag);
    hipMemsetAsync(deg, 0, (size_t)200000 * 4, stream);  // deg + cnt

    k_deghist<<<NE / 256, 256, 0, stream>>>(ei, ew, deg, cnt, flag);
    k_dinv<<<(NN + 255) / 256, 256, 0, stream>>>(deg);
    k_scan<<<1, 1024, 0, stream>>>(cnt, rowptr, wptr);
    k_fill<<<NE / 256, 256, 0, stream>>>(ei, ew, deg, wptr, csr, flag);
    k_wcat<<<336, 256, 0, stream>>>(Wx, theta, bg, convb, Wl, Wf, biasP, WlF, flag);

    k_gath<true ><<<25000, 256, 0, stream>>>(rowptr, csr, h,    Tx1f, flag);
    k_gath<false><<<25000, 256, 0, stream>>>(rowptr, csr, Tx1f, agg2, flag);

    k_gates<<<(NN + 63) / 64, 256, 0, stream>>>(x, h, c, Tx1f, agg2,
                                                Wf, biasP, WlF, bl,
                                                outF, h0o, c0o, flag);
}